// Round 1
// baseline (402.470 us; speedup 1.0000x reference)
//
#include <hip/hip_runtime.h>
#include <hip/hip_bf16.h>
#include <stdint.h>

#define S_LEN 2048
#define HID_DIM 2048
#define HQ 32
#define HKV 8
#define NPROJ 5120   // 2048 q | 512 k | 512 v | 2048 g
#define QSCALE 0.125f

using f32x4 = __attribute__((ext_vector_type(4))) float;
using bfrag = __attribute__((ext_vector_type(8))) short;

__device__ __forceinline__ unsigned short f2bf(float f) {
    union { float f; unsigned u; } a; a.f = f;
    unsigned r = a.u + 0x7fffu + ((a.u >> 16) & 1u);
    return (unsigned short)(r >> 16);
}
__device__ __forceinline__ float bf2f(unsigned short h) {
    union { unsigned u; float f; } a; a.u = ((unsigned)h) << 16;
    return a.f;
}

// ---------------- x fp32 -> bf16 ----------------
__global__ void k_convert_x(const float* __restrict__ x, unsigned short* __restrict__ xb, int n4) {
    int i = blockIdx.x * blockDim.x + threadIdx.x;
    if (i < n4) {
        float4 v = ((const float4*)x)[i];
        ushort4 o;
        o.x = f2bf(v.x); o.y = f2bf(v.y); o.z = f2bf(v.z); o.w = f2bf(v.w);
        ((ushort4*)xb)[i] = o;
    }
}

// ---------------- W [K][N] fp32 -> Wt bf16 [N][K] (at row offset) ----------------
__global__ void k_transpose_w(const float* __restrict__ src, unsigned short* __restrict__ dst,
                              int K, int N, int rowOff) {
    __shared__ float tile[32][33];
    int n0 = blockIdx.x * 32;
    int k0 = blockIdx.y * 32;
    int lx = threadIdx.x & 31;
    int ly = threadIdx.x >> 5;  // 0..7
#pragma unroll
    for (int i = 0; i < 4; i++) {
        int r = ly + i * 8;
        tile[r][lx] = src[(size_t)(k0 + r) * N + n0 + lx];
    }
    __syncthreads();
#pragma unroll
    for (int i = 0; i < 4; i++) {
        int nn = ly + i * 8;
        dst[(size_t)(rowOff + n0 + nn) * K + k0 + lx] = f2bf(tile[lx][nn]);
    }
}

// ---------------- bf16 GEMM: A[M][K] x Bt[N][K] -> C[M][N] fp32 ----------------
// 128x128 tile, BK=64, 4 waves (2x2 of 64x64), padded LDS rows (72 bf16 = 144B, 16B aligned)
__global__ __launch_bounds__(256) void k_gemm_bf16(
        const unsigned short* __restrict__ A,
        const unsigned short* __restrict__ Bt,
        float* __restrict__ C,
        int M, int N, int K) {
    __shared__ __align__(16) unsigned short As[128 * 72];
    __shared__ __align__(16) unsigned short Bs[128 * 72];
    const int tid = threadIdx.x;
    const int lane = tid & 63;
    const int w = tid >> 6;
    const int wm = (w >> 1) * 64, wn = (w & 1) * 64;
    const int bm0 = blockIdx.y * 128, bn0 = blockIdx.x * 128;
    const int lr = lane & 15;
    const int lk = (lane >> 4) * 8;

    f32x4 acc[4][4] = {};

    for (int k0 = 0; k0 < K; k0 += 64) {
        __syncthreads();
#pragma unroll
        for (int p = 0; p < 4; p++) {
            int c = p * 256 + tid;
            int row = c >> 3, col8 = (c & 7) * 8;
            uint4 va = *(const uint4*)&A[(size_t)(bm0 + row) * K + k0 + col8];
            *(uint4*)&As[row * 72 + col8] = va;
            uint4 vb = *(const uint4*)&Bt[(size_t)(bn0 + row) * K + k0 + col8];
            *(uint4*)&Bs[row * 72 + col8] = vb;
        }
        __syncthreads();
#pragma unroll
        for (int kc = 0; kc < 2; kc++) {
            bfrag af[4], bfr[4];
#pragma unroll
            for (int t = 0; t < 4; t++)
                af[t] = *(const bfrag*)&As[(wm + t * 16 + lr) * 72 + kc * 32 + lk];
#pragma unroll
            for (int t = 0; t < 4; t++)
                bfr[t] = *(const bfrag*)&Bs[(wn + t * 16 + lr) * 72 + kc * 32 + lk];
#pragma unroll
            for (int mt = 0; mt < 4; mt++)
#pragma unroll
                for (int nt = 0; nt < 4; nt++)
                    acc[mt][nt] = __builtin_amdgcn_mfma_f32_16x16x32_bf16(af[mt], bfr[nt], acc[mt][nt], 0, 0, 0);
        }
    }
    const int orow = (lane >> 4) * 4;
#pragma unroll
    for (int mt = 0; mt < 4; mt++)
#pragma unroll
        for (int nt = 0; nt < 4; nt++)
#pragma unroll
            for (int j = 0; j < 4; j++)
                C[(size_t)(bm0 + wm + mt * 16 + orow + j) * N + bn0 + wn + nt * 16 + lr] = acc[mt][nt][j];
}

// ---------------- projection epilogue: RoPE / gate / layout shuffles ----------------
__global__ void k_epilogue(const float* __restrict__ proj,
                           const float* __restrict__ cosb, const float* __restrict__ sinb,
                           const float* __restrict__ bg,
                           unsigned short* __restrict__ qb,    // [HQ][S][64], pre-scaled
                           unsigned short* __restrict__ kbuf,  // [HKV][S][64]
                           unsigned short* __restrict__ vt,    // [HKV][64][S]
                           unsigned short* __restrict__ alpha, // [S][2048]
                           float* __restrict__ outk, float* __restrict__ outv) {
    int idx = blockIdx.x * 256 + threadIdx.x;
    int s = idx / NPROJ;
    int n = idx - s * NPROJ;
    float val = proj[idx];
    if (n < 2048) {                 // q + RoPE
        int h = n >> 6, d = n & 63;
        float c = cosb[(s << 6) + d], sn = sinb[(s << 6) + d];
        float partner = proj[(size_t)s * NPROJ + (d < 32 ? n + 32 : n - 32)];
        float rot = (d < 32) ? -partner : partner;
        float o = val * c + rot * sn;
        qb[((size_t)h * S_LEN + s) * 64 + d] = f2bf(o * QSCALE);
    } else if (n < 2560) {          // k + RoPE (+ fp32 out)
        int m = n - 2048;
        int h = m >> 6, d = m & 63;
        float c = cosb[(s << 6) + d], sn = sinb[(s << 6) + d];
        float partner = proj[(size_t)s * NPROJ + (d < 32 ? n + 32 : n - 32)];
        float rot = (d < 32) ? -partner : partner;
        float o = val * c + rot * sn;
        size_t oidx = ((size_t)h * S_LEN + s) * 64 + d;
        kbuf[oidx] = f2bf(o);
        outk[oidx] = o;
    } else if (n < 3072) {          // v transposed (+ fp32 out)
        int m = n - 2560;
        int h = m >> 6, d = m & 63;
        vt[((size_t)h * 64 + d) * S_LEN + s] = f2bf(val);
        outv[((size_t)h * S_LEN + s) * 64 + d] = val;
    } else {                        // gate
        int m = n - 3072;
        float a = 1.0f / (1.0f + __expf(-(val + bg[m])));
        alpha[(size_t)s * 2048 + m] = f2bf(a);
    }
}

// ---------------- flash attention (causal, GQA) ----------------
// block = (qblk of 64 rows, head). 4 waves x 16 q-rows. KV tile = 64.
__global__ __launch_bounds__(256) void k_attn(
        const unsigned short* __restrict__ qb,
        const unsigned short* __restrict__ kbuf,
        const unsigned short* __restrict__ vt,
        float* __restrict__ ao) {   // [HQ][S][64]
    __shared__ __align__(16) unsigned short Ks[64 * 72];       // [kv][d]
    __shared__ __align__(16) unsigned short Vs[64 * 72];       // [d][kv]
    __shared__ __align__(16) unsigned short Ps[4][16 * 72];    // per-wave P tile
    const int qblk = gridDim.x - 1 - blockIdx.x;  // heavy blocks first
    const int h = blockIdx.y;
    const int hk = h >> 2;
    const int tid = threadIdx.x;
    const int lane = tid & 63;
    const int w = tid >> 6;
    const int lr = lane & 15;
    const int lk = (lane >> 4) * 8;
    const int r0 = qblk * 64 + w * 16;

    bfrag qf[2];
    {
        const unsigned short* qrow = &qb[((size_t)h * S_LEN + r0 + lr) * 64];
        qf[0] = *(const bfrag*)&qrow[lk];
        qf[1] = *(const bfrag*)&qrow[32 + lk];
    }
    float m_r[4], l_r[4];
    f32x4 o_acc[4] = {};
#pragma unroll
    for (int j = 0; j < 4; j++) { m_r[j] = -1e30f; l_r[j] = 0.0f; }

    const unsigned short* Kg = &kbuf[(size_t)hk * S_LEN * 64];
    const unsigned short* Vg = &vt[(size_t)hk * 64 * S_LEN];

    for (int kb = 0; kb <= qblk; kb++) {
        __syncthreads();
#pragma unroll
        for (int p = 0; p < 2; p++) {
            int c = p * 256 + tid;
            int row = c >> 3, col8 = (c & 7) * 8;
            uint4 v = *(const uint4*)&Kg[(size_t)(kb * 64 + row) * 64 + col8];
            *(uint4*)&Ks[row * 72 + col8] = v;
            uint4 v2 = *(const uint4*)&Vg[(size_t)row * S_LEN + kb * 64 + col8];
            *(uint4*)&Vs[row * 72 + col8] = v2;
        }
        __syncthreads();
        // QK^T -> 16x64 scores
        f32x4 sacc[4] = {};
#pragma unroll
        for (int kc = 0; kc < 2; kc++) {
            bfrag kf[4];
#pragma unroll
            for (int g = 0; g < 4; g++)
                kf[g] = *(const bfrag*)&Ks[(g * 16 + lr) * 72 + kc * 32 + lk];
#pragma unroll
            for (int g = 0; g < 4; g++)
                sacc[g] = __builtin_amdgcn_mfma_f32_16x16x32_bf16(qf[kc], kf[g], sacc[g], 0, 0, 0);
        }
        if (kb == qblk) {  // diagonal masking
#pragma unroll
            for (int g = 0; g < 4; g++)
#pragma unroll
                for (int j = 0; j < 4; j++) {
                    int col = lr + 16 * g;
                    int row = w * 16 + (lane >> 4) * 4 + j;
                    if (col > row) sacc[g][j] = -1e30f;
                }
        }
        float psum[4];
#pragma unroll
        for (int j = 0; j < 4; j++) {
            float tv = fmaxf(fmaxf(sacc[0][j], sacc[1][j]), fmaxf(sacc[2][j], sacc[3][j]));
#pragma unroll
            for (int msk = 1; msk < 16; msk <<= 1)
                tv = fmaxf(tv, __shfl_xor(tv, msk, 64));
            float mnew = fmaxf(m_r[j], tv);
            float sc = __expf(m_r[j] - mnew);
            m_r[j] = mnew;
            l_r[j] *= sc;
#pragma unroll
            for (int g = 0; g < 4; g++) o_acc[g][j] *= sc;
            psum[j] = 0.0f;
        }
#pragma unroll
        for (int g = 0; g < 4; g++)
#pragma unroll
            for (int j = 0; j < 4; j++) {
                float p = __expf(sacc[g][j] - m_r[j]);
                psum[j] += p;
                Ps[w][((lane >> 4) * 4 + j) * 72 + lr + 16 * g] = f2bf(p);
            }
#pragma unroll
        for (int j = 0; j < 4; j++) {
            float pv = psum[j];
#pragma unroll
            for (int msk = 1; msk < 16; msk <<= 1)
                pv += __shfl_xor(pv, msk, 64);
            l_r[j] += pv;
        }
        __syncthreads();
        // PV
#pragma unroll
        for (int kc = 0; kc < 2; kc++) {
            bfrag pf = *(const bfrag*)&Ps[w][lr * 72 + kc * 32 + lk];
#pragma unroll
            for (int g = 0; g < 4; g++) {
                bfrag vf = *(const bfrag*)&Vs[(g * 16 + lr) * 72 + kc * 32 + lk];
                o_acc[g] = __builtin_amdgcn_mfma_f32_16x16x32_bf16(pf, vf, o_acc[g], 0, 0, 0);
            }
        }
    }
    float inv[4];
#pragma unroll
    for (int j = 0; j < 4; j++) inv[j] = 1.0f / (l_r[j] + 1e-9f);
#pragma unroll
    for (int g = 0; g < 4; g++)
#pragma unroll
        for (int j = 0; j < 4; j++) {
            int row = r0 + (lane >> 4) * 4 + j;
            ao[((size_t)h * S_LEN + row) * 64 + lr + 16 * g] = o_acc[g][j] * inv[j];
        }
}

// ---------------- GroupNorm(D=64) * gate -> bf16 ----------------
__global__ void k_gn(const float* __restrict__ ao, const unsigned short* __restrict__ alpha,
                     const float* __restrict__ gnw, const float* __restrict__ gnb,
                     unsigned short* __restrict__ gno) {
    int row = blockIdx.x * 4 + (threadIdx.x >> 6);  // row = h*2048 + s
    int d = threadIdx.x & 63;
    int h = row >> 11;
    int s = row & 2047;
    float v = ao[(size_t)row * 64 + d];
    float mu = v;
#pragma unroll
    for (int msk = 1; msk < 64; msk <<= 1) mu += __shfl_xor(mu, msk, 64);
    mu *= (1.0f / 64.0f);
    float dv = v - mu;
    float var = dv * dv;
#pragma unroll
    for (int msk = 1; msk < 64; msk <<= 1) var += __shfl_xor(var, msk, 64);
    var *= (1.0f / 64.0f);
    int col = (h << 6) + d;
    float g = dv * rsqrtf(var + 1e-5f) * gnw[col] + gnb[col];
    float a = bf2f(alpha[(size_t)s * 2048 + col]);
    gno[(size_t)s * 2048 + col] = f2bf(g * a);
}

extern "C" void kernel_launch(void* const* d_in, const int* in_sizes, int n_in,
                              void* d_out, int out_size, void* d_ws, size_t ws_size,
                              hipStream_t stream) {
    const float* x   = (const float*)d_in[0];
    const float* rc  = (const float*)d_in[1];
    const float* rs  = (const float*)d_in[2];
    const float* Wq  = (const float*)d_in[3];
    const float* Wk  = (const float*)d_in[4];
    const float* Wv  = (const float*)d_in[5];
    const float* Wo  = (const float*)d_in[6];
    const float* Wg  = (const float*)d_in[7];
    const float* bg  = (const float*)d_in[8];
    const float* gnw = (const float*)d_in[9];
    const float* gnb = (const float*)d_in[10];
    float* out = (float*)d_out;

    char* ws = (char*)d_ws;
    // phase-1 regions
    unsigned short* xb    = (unsigned short*)(ws);                      // 8 MB
    unsigned short* WcatT = (unsigned short*)(ws + 8388608);            // 20 MB, dead after proj GEMM
    unsigned short* WoT   = (unsigned short*)(ws + 29360128);           // 8 MB
    float*          proj  = (float*)(ws + 37748736);                    // 40 MB, dead after epilogue
    // phase-2 regions (reuse WcatT)
    unsigned short* alpha = (unsigned short*)(ws + 8388608);            // 8 MB
    unsigned short* qb    = (unsigned short*)(ws + 16777216);           // 8 MB
    unsigned short* kbuf  = (unsigned short*)(ws + 25165824);           // 2 MB
    unsigned short* vt    = (unsigned short*)(ws + 27262976);           // 2 MB
    // phase-3 regions (reuse proj)
    float*          ao    = (float*)(ws + 37748736);                    // 16 MB
    unsigned short* gno   = (unsigned short*)(ws + 54525952);           // 8 MB
    // total ws footprint: 76 MB

    hipLaunchKernelGGL(k_convert_x, dim3(4096), dim3(256), 0, stream, x, xb, 2048 * 2048 / 4);
    hipLaunchKernelGGL(k_transpose_w, dim3(64, 64), dim3(256), 0, stream, Wq, WcatT, 2048, 2048, 0);
    hipLaunchKernelGGL(k_transpose_w, dim3(16, 64), dim3(256), 0, stream, Wk, WcatT, 2048, 512, 2048);
    hipLaunchKernelGGL(k_transpose_w, dim3(16, 64), dim3(256), 0, stream, Wv, WcatT, 2048, 512, 2560);
    hipLaunchKernelGGL(k_transpose_w, dim3(64, 64), dim3(256), 0, stream, Wg, WcatT, 2048, 2048, 3072);
    hipLaunchKernelGGL(k_transpose_w, dim3(64, 64), dim3(256), 0, stream, Wo, WoT, 2048, 2048, 0);

    hipLaunchKernelGGL(k_gemm_bf16, dim3(5120 / 128, 2048 / 128), dim3(256), 0, stream,
                       xb, WcatT, proj, 2048, 5120, 2048);

    float* outk = out + (size_t)4 * 1024 * 1024;
    float* outv = out + (size_t)5 * 1024 * 1024;
    hipLaunchKernelGGL(k_epilogue, dim3(2048 * 5120 / 256), dim3(256), 0, stream,
                       proj, rc, rs, bg, qb, kbuf, vt, alpha, outk, outv);

    hipLaunchKernelGGL(k_attn, dim3(32, 32), dim3(256), 0, stream, qb, kbuf, vt, ao);

    hipLaunchKernelGGL(k_gn, dim3(32 * 2048 / 4), dim3(256), 0, stream, ao, alpha, gnw, gnb, gno);

    hipLaunchKernelGGL(k_gemm_bf16, dim3(2048 / 128, 2048 / 128), dim3(256), 0, stream,
                       gno, WoT, out, 2048, 2048, 2048);
}